// Round 4
// baseline (51.971 us; speedup 1.0000x reference)
//
#include <hip/hip_runtime.h>
#include <math.h>

#define H       2048
#define E       64
#define TOKENS  16384
#define BATCH   4

typedef _Float16 f16x8 __attribute__((ext_vector_type(8)));
typedef float    f32x4 __attribute__((ext_vector_type(4)));

// ws float offsets
#define WHI_OFF  0          // 131072 f16 = 65536 floats
#define WLO_OFF  65536      // 131072 f16
#define PART_OFF 131072     // 512 blocks * 128 floats (psum[64] | cnt[64])

// ---- W fp32 -> tiled f16 hi/lo in MFMA B-fragment order (unchanged, proven) ----
// slot s = (kk*4 + et)*64 + lane; element j = Whl[e=et*16+(l&15)][kk*32+(l>>4)*8+j]
__global__ __launch_bounds__(256)
void wconv(const float* __restrict__ W, _Float16* __restrict__ whi, _Float16* __restrict__ wlo)
{
    const int s  = blockIdx.x * 256 + threadIdx.x;   // 0..16383
    const int kk = s >> 8;
    const int et = (s >> 6) & 3;
    const int l  = s & 63;
    const int e  = et * 16 + (l & 15);
    const int kb = kk * 32 + ((l >> 4) << 3);
    const float4 a = *(const float4*)(W + (size_t)e * H + kb);
    const float4 b = *(const float4*)(W + (size_t)e * H + kb + 4);
    const float xv[8] = {a.x, a.y, a.z, a.w, b.x, b.y, b.z, b.w};
    f16x8 hi, lo;
    #pragma unroll
    for (int j = 0; j < 8; ++j) {
        const _Float16 h = (_Float16)xv[j];
        hi[j] = h;
        lo[j] = (_Float16)(xv[j] - (float)h);
    }
    *(f16x8*)(whi + (size_t)s * 8) = hi;
    *(f16x8*)(wlo + (size_t)s * 8) = lo;
}

// ---- main: 512 blocks x 512 thr (2 blocks/CU); wave = (tg 0..1, ks 0..3) ----
__global__ __launch_bounds__(512, 4)
void router_main(const float* __restrict__ x,
                 const _Float16* __restrict__ whi,
                 const _Float16* __restrict__ wlo,
                 float* __restrict__ out,
                 float* __restrict__ part)
{
    __shared__ float lds[8192];   // 32 KB: [2 tg][4 ks][16 t][64 e] partials, then reused

    const int tid = threadIdx.x;
    const int l   = tid & 63;
    const int w   = tid >> 6;     // 0..7
    const int tg  = w & 1;
    const int ks  = w >> 1;

    const int    trow  = blockIdx.x * 32 + tg * 16 + (l & 15);     // A row = lane&15
    const float* xbase = x + (size_t)trow * H + ks * 512 + ((l >> 4) << 3);
    const f16x8* bh_base = (const f16x8*)whi + (size_t)(ks * 16) * 256 + l;
    const f16x8* bl_base = (const f16x8*)wlo + (size_t)(ks * 16) * 256 + l;

    f32x4 acc[4];
    #pragma unroll
    for (int et = 0; et < 4; ++et) acc[et] = (f32x4){0.f, 0.f, 0.f, 0.f};

    float4 a0 = *(const float4*)xbase;
    float4 a1 = *(const float4*)(xbase + 4);

    #pragma unroll
    for (int kk = 0; kk < 16; ++kk) {
        float4 n0 = a0, n1 = a1;
        if (kk < 15) {   // prefetch next A (HBM) under this step's compute
            n0 = *(const float4*)(xbase + (kk + 1) * 32);
            n1 = *(const float4*)(xbase + (kk + 1) * 32 + 4);
        }
        f16x8 bh[4], bl[4];
        #pragma unroll
        for (int et = 0; et < 4; ++et) {
            bh[et] = bh_base[kk * 256 + et * 64];
            bl[et] = bl_base[kk * 256 + et * 64];
        }
        const float xv[8] = {a0.x, a0.y, a0.z, a0.w, a1.x, a1.y, a1.z, a1.w};
        f16x8 ahi, alo;
        #pragma unroll
        for (int j = 0; j < 8; ++j) {
            const _Float16 h = (_Float16)xv[j];
            ahi[j] = h;
            alo[j] = (_Float16)(xv[j] - (float)h);
        }
        #pragma unroll
        for (int et = 0; et < 4; ++et) {
            acc[et] = __builtin_amdgcn_mfma_f32_16x16x32_f16(ahi, bh[et], acc[et], 0, 0, 0);
            acc[et] = __builtin_amdgcn_mfma_f32_16x16x32_f16(ahi, bl[et], acc[et], 0, 0, 0);
            acc[et] = __builtin_amdgcn_mfma_f32_16x16x32_f16(alo, bh[et], acc[et], 0, 0, 0);
        }
        a0 = n0; a1 = n1;
    }

    // ---- write K-slice partials: C row=(l>>4)*4+i (token-local), col=lane&15
    #pragma unroll
    for (int et = 0; et < 4; ++et)
        #pragma unroll
        for (int i = 0; i < 4; ++i) {
            const int t = ((l >> 4) << 2) + i;
            const int e = et * 16 + (l & 15);
            lds[((tg * 4 + ks) * 16 + t) * 64 + e] = acc[et][i];
        }
    __syncthreads();

    // ---- reduce over ks (512 lanes x 4 outputs), write final [32][65]
    {
        const int t_g = tid >> 4;            // 0..31
        const int e4  = (tid & 15) * 4;
        const int tg2 = t_g >> 4, tl = t_g & 15;
        float s0 = 0.f, s1 = 0.f, s2 = 0.f, s3 = 0.f;
        #pragma unroll
        for (int k2 = 0; k2 < 4; ++k2) {
            const float4 v = *(const float4*)&lds[((tg2 * 4 + k2) * 16 + tl) * 64 + e4];
            s0 += v.x; s1 += v.y; s2 += v.z; s3 += v.w;
        }
        __syncthreads();    // all partial reads done before overwrite
        lds[t_g * 65 + e4 + 0] = s0;
        lds[t_g * 65 + e4 + 1] = s1;
        lds[t_g * 65 + e4 + 2] = s2;
        lds[t_g * 65 + e4 + 3] = s3;
    }
    __syncthreads();

    // ---- wave-0 epilogue: lanes 0..31 = tokens (proven serial structure)
    int i1 = 0, i2 = 0;
    if (w == 0 && l < 32) {
        float lg[64];
        #pragma unroll
        for (int e = 0; e < 64; ++e) lg[e] = lds[l * 65 + e];
        float v1 = lg[0];
        #pragma unroll
        for (int e = 1; e < 64; ++e) { if (lg[e] > v1) { v1 = lg[e]; i1 = e; } }
        float v2 = -INFINITY;
        #pragma unroll
        for (int e = 0; e < 64; ++e) { if (e != i1 && lg[e] > v2) { v2 = lg[e]; i2 = e; } }
        float den = 0.f;
        #pragma unroll
        for (int e = 0; e < 64; ++e) den += __expf(lg[e] - v1);
        const float inv_den = 1.f / den;
        const float s1 = inv_den;                    // exp(v1-v1)/den
        const float s2 = __expf(v2 - v1) * inv_den;
        const float rs = 1.f / (s1 + s2 + 1e-20f);
        const int gt = blockIdx.x * 32 + l;
        *(float2*)&out[2 * gt]              = make_float2((float)i1, (float)i2);
        *(float2*)&out[2 * TOKENS + 2 * gt] = make_float2(s1 * rs, s2 * rs);
        // scores, rotated columns for conflict-free column sums
        #pragma unroll
        for (int e = 0; e < 64; ++e)
            lds[4096 + l * 64 + ((e + l) & 63)] = __expf(lg[e] - v1) * inv_den;
    }
    __syncthreads();
    if (w == 0) {
        float cs = 0.f;                  // expert l's score sum over 32 tokens
        #pragma unroll
        for (int r = 0; r < 32; ++r) cs += lds[4096 + r * 64 + ((l + r) & 63)];
        part[blockIdx.x * 128 + l] = cs;
        lds[6144 + l] = 0.f;
    }
    __syncthreads();
    if (w == 0 && l < 32) {
        atomicAdd(&lds[6144 + i1], 1.f);
        atomicAdd(&lds[6144 + i2], 1.f);
    }
    __syncthreads();
    if (w == 0) part[blockIdx.x * 128 + 64 + l] = lds[6144 + l];
}

// ---- aux loss finalize: reduce 512 per-block partials ----
__global__ __launch_bounds__(256)
void router_aux(const float* __restrict__ part, float* __restrict__ out)
{
    const int tid = threadIdx.x;    // 256 = BATCH*E
    const int b = tid >> 6, e = tid & 63;
    float ps = 0.f, ct = 0.f;
    for (int j = 0; j < 128; ++j) {          // 128 blocks per batch
        const int base = (b * 128 + j) * 128;
        ps += part[base + e];                // coalesced: lanes -> consecutive e
        ct += part[base + 64 + e];
    }
    // ce = ct * E/(S*k); meanprob = ps/S
    float val = ct * (64.0f / (4096.0f * 2.0f)) * (ps / 4096.0f);
    #pragma unroll
    for (int off = 32; off > 0; off >>= 1) val += __shfl_xor(val, off, 64);
    __shared__ float red[4];
    if ((tid & 63) == 0) red[tid >> 6] = val;
    __syncthreads();
    if (tid == 0)
        out[4 * TOKENS] = (red[0] + red[1] + red[2] + red[3]) * (0.001f / 4.0f);
}

extern "C" void kernel_launch(void* const* d_in, const int* in_sizes, int n_in,
                              void* d_out, int out_size, void* d_ws, size_t ws_size,
                              hipStream_t stream)
{
    (void)in_sizes; (void)n_in; (void)out_size; (void)ws_size;
    const float* x = (const float*)d_in[0];
    const float* W = (const float*)d_in[1];
    float* out = (float*)d_out;
    float* ws  = (float*)d_ws;

    _Float16* whi = (_Float16*)(ws + WHI_OFF);
    _Float16* wlo = (_Float16*)(ws + WLO_OFF);
    float*    part = ws + PART_OFF;

    hipLaunchKernelGGL(wconv, dim3(64), dim3(256), 0, stream, W, whi, wlo);
    hipLaunchKernelGGL(router_main, dim3(TOKENS / 32), dim3(512), 0, stream,
                       x, whi, wlo, out, part);
    hipLaunchKernelGGL(router_aux, dim3(1), dim3(256), 0, stream, part, out);
}

// Round 5
// 49.059 us; speedup vs baseline: 1.0593x; 1.0593x over previous
//
#include <hip/hip_runtime.h>
#include <math.h>

#define H       2048
#define E       64
#define TOKENS  16384
#define BATCH   4

typedef _Float16 f16x8  __attribute__((ext_vector_type(8)));
typedef float    f32x16 __attribute__((ext_vector_type(16)));

// ws float offsets
#define WHI_OFF  0          // 131072 f16 = 65536 floats
#define WLO_OFF  65536      // 131072 f16
#define PART_OFF 131072     // 512 blocks * 128 floats (psum[64] | cnt[64])

// ---- W fp32 -> tiled f16 hi/lo in 32x32x16 B-fragment order ----
// slot s = (kg*2 + et)*64 + l ; e = et*32 + (l&31) ; k = kg*16 + (l>>5)*8 + j
__global__ __launch_bounds__(256)
void wconv(const float* __restrict__ W, _Float16* __restrict__ whi, _Float16* __restrict__ wlo)
{
    const int s  = blockIdx.x * 256 + threadIdx.x;   // 0..16383
    const int kg = s >> 7;          // 0..127 (K=16 group)
    const int et = (s >> 6) & 1;    // expert tile 0..1
    const int l  = s & 63;
    const int e  = et * 32 + (l & 31);
    const int kb = kg * 16 + ((l >> 5) << 3);
    const float4 a = *(const float4*)(W + (size_t)e * H + kb);
    const float4 b = *(const float4*)(W + (size_t)e * H + kb + 4);
    const float xv[8] = {a.x, a.y, a.z, a.w, b.x, b.y, b.z, b.w};
    f16x8 hi, lo;
    #pragma unroll
    for (int j = 0; j < 8; ++j) {
        const _Float16 h = (_Float16)xv[j];
        hi[j] = h;
        lo[j] = (_Float16)(xv[j] - (float)h);
    }
    *(f16x8*)(whi + (size_t)s * 8) = hi;
    *(f16x8*)(wlo + (size_t)s * 8) = lo;
}

// ---- main: 512 blocks x 512 thr (2 blocks/CU, 4 waves/SIMD) ----
// wave = ks 0..7 (K-slice of 256); each wave: 32 tokens x 64 experts via 2x mfma_32x32x16
__global__ __launch_bounds__(512, 4)
void router_main(const float* __restrict__ x,
                 const _Float16* __restrict__ whi,
                 const _Float16* __restrict__ wlo,
                 float* __restrict__ out,
                 float* __restrict__ part)
{
    __shared__ float lds[16384];   // 64 KB: [8 ks][32 t][64 e] partials, then reused

    const int tid = threadIdx.x;
    const int l   = tid & 63;
    const int ks  = tid >> 6;      // 0..7

    const int    trow = blockIdx.x * 32 + (l & 31);          // A row = lane&31
    const float* xb   = x + (size_t)trow * H + ks * 256 + ((l >> 5) << 3);
    const f16x8* bh   = (const f16x8*)whi + (size_t)(ks * 16) * 128 + l;  // 128 slots per kg
    const f16x8* blp  = (const f16x8*)wlo + (size_t)(ks * 16) * 128 + l;

    f32x16 acc[2];
    #pragma unroll
    for (int et = 0; et < 2; ++et)
        #pragma unroll
        for (int i = 0; i < 16; ++i) acc[et][i] = 0.f;

    float4 a0 = *(const float4*)xb;
    float4 a1 = *(const float4*)(xb + 4);
    f16x8 b0h = bh[0],  b1h = bh[64];
    f16x8 b0l = blp[0], b1l = blp[64];

    #pragma unroll
    for (int kk = 0; kk < 16; ++kk) {
        float4 n0 = a0, n1 = a1;
        f16x8 nb0h = b0h, nb1h = b1h, nb0l = b0l, nb1l = b1l;
        if (kk < 15) {   // prefetch next step (A from HBM, B from L1/L2)
            n0   = *(const float4*)(xb + (kk + 1) * 16);
            n1   = *(const float4*)(xb + (kk + 1) * 16 + 4);
            nb0h = bh[(kk + 1) * 128];       nb1h = bh[(kk + 1) * 128 + 64];
            nb0l = blp[(kk + 1) * 128];      nb1l = blp[(kk + 1) * 128 + 64];
        }
        const float xv[8] = {a0.x, a0.y, a0.z, a0.w, a1.x, a1.y, a1.z, a1.w};
        f16x8 ahi, alo;
        #pragma unroll
        for (int j = 0; j < 8; ++j) {
            const _Float16 h = (_Float16)xv[j];
            ahi[j] = h;
            alo[j] = (_Float16)(xv[j] - (float)h);
        }
        acc[0] = __builtin_amdgcn_mfma_f32_32x32x16_f16(ahi, b0h, acc[0], 0, 0, 0);
        acc[0] = __builtin_amdgcn_mfma_f32_32x32x16_f16(ahi, b0l, acc[0], 0, 0, 0);
        acc[0] = __builtin_amdgcn_mfma_f32_32x32x16_f16(alo, b0h, acc[0], 0, 0, 0);
        acc[1] = __builtin_amdgcn_mfma_f32_32x32x16_f16(ahi, b1h, acc[1], 0, 0, 0);
        acc[1] = __builtin_amdgcn_mfma_f32_32x32x16_f16(ahi, b1l, acc[1], 0, 0, 0);
        acc[1] = __builtin_amdgcn_mfma_f32_32x32x16_f16(alo, b1h, acc[1], 0, 0, 0);
        a0 = n0; a1 = n1;
        b0h = nb0h; b1h = nb1h; b0l = nb0l; b1l = nb1l;
    }

    // ---- write K-slice partials: row=(r&3)+8*(r>>2)+4*(l>>5), col=et*32+(l&31)
    #pragma unroll
    for (int et = 0; et < 2; ++et)
        #pragma unroll
        for (int r = 0; r < 16; ++r) {
            const int row = (r & 3) + 8 * (r >> 2) + 4 * (l >> 5);
            lds[(ks * 32 + row) * 64 + et * 32 + (l & 31)] = acc[et][r];
        }
    __syncthreads();

    // ---- reduce over 8 ks (512 thr: t=tid>>4, c4=(tid&15)*4), write [32][65]
    {
        const int t = tid >> 4, c4 = (tid & 15) * 4;
        float s0 = 0.f, s1 = 0.f, s2 = 0.f, s3 = 0.f;
        #pragma unroll
        for (int k2 = 0; k2 < 8; ++k2) {
            const float4 v = *(const float4*)&lds[(k2 * 32 + t) * 64 + c4];
            s0 += v.x; s1 += v.y; s2 += v.z; s3 += v.w;
        }
        __syncthreads();    // all partial reads done before overwrite
        lds[t * 65 + c4 + 0] = s0;
        lds[t * 65 + c4 + 1] = s1;
        lds[t * 65 + c4 + 2] = s2;
        lds[t * 65 + c4 + 3] = s3;
    }
    __syncthreads();

    // ---- wave-0 epilogue: lanes 0..31 = tokens (proven serial structure)
    const int w = tid >> 6;
    #define SC_OFF   2112
    #define HIST_OFF 6272
    int i1 = 0, i2 = 0;
    if (w == 0 && l < 32) {
        float lg[64];
        #pragma unroll
        for (int e = 0; e < 64; ++e) lg[e] = lds[l * 65 + e];
        float v1 = lg[0];
        #pragma unroll
        for (int e = 1; e < 64; ++e) { if (lg[e] > v1) { v1 = lg[e]; i1 = e; } }
        float v2 = -INFINITY;
        #pragma unroll
        for (int e = 0; e < 64; ++e) { if (e != i1 && lg[e] > v2) { v2 = lg[e]; i2 = e; } }
        float den = 0.f;
        #pragma unroll
        for (int e = 0; e < 64; ++e) den += __expf(lg[e] - v1);
        const float inv_den = 1.f / den;
        const float s1 = inv_den;                    // exp(v1-v1)/den
        const float s2 = __expf(v2 - v1) * inv_den;
        const float rs = 1.f / (s1 + s2 + 1e-20f);
        const int gt = blockIdx.x * 32 + l;
        *(float2*)&out[2 * gt]              = make_float2((float)i1, (float)i2);
        *(float2*)&out[2 * TOKENS + 2 * gt] = make_float2(s1 * rs, s2 * rs);
        // scores, rotated columns for conflict-free column sums
        #pragma unroll
        for (int e = 0; e < 64; ++e)
            lds[SC_OFF + l * 64 + ((e + l) & 63)] = __expf(lg[e] - v1) * inv_den;
    }
    __syncthreads();
    if (w == 0) {
        float cs = 0.f;                  // expert l's score sum over 32 tokens
        #pragma unroll
        for (int r = 0; r < 32; ++r) cs += lds[SC_OFF + r * 64 + ((l + r) & 63)];
        part[blockIdx.x * 128 + l] = cs;
        lds[HIST_OFF + l] = 0.f;
    }
    __syncthreads();
    if (w == 0 && l < 32) {
        atomicAdd(&lds[HIST_OFF + i1], 1.f);
        atomicAdd(&lds[HIST_OFF + i2], 1.f);
    }
    __syncthreads();
    if (w == 0) part[blockIdx.x * 128 + 64 + l] = lds[HIST_OFF + l];
}

// ---- aux loss finalize: reduce 512 per-block partials ----
__global__ __launch_bounds__(256)
void router_aux(const float* __restrict__ part, float* __restrict__ out)
{
    const int tid = threadIdx.x;    // 256 = BATCH*E
    const int b = tid >> 6, e = tid & 63;
    float ps = 0.f, ct = 0.f;
    for (int j = 0; j < 128; ++j) {          // 128 blocks per batch
        const int base = (b * 128 + j) * 128;
        ps += part[base + e];                // coalesced: lanes -> consecutive e
        ct += part[base + 64 + e];
    }
    // ce = ct * E/(S*k); meanprob = ps/S
    float val = ct * (64.0f / (4096.0f * 2.0f)) * (ps / 4096.0f);
    #pragma unroll
    for (int off = 32; off > 0; off >>= 1) val += __shfl_xor(val, off, 64);
    __shared__ float red[4];
    if ((tid & 63) == 0) red[tid >> 6] = val;
    __syncthreads();
    if (tid == 0)
        out[4 * TOKENS] = (red[0] + red[1] + red[2] + red[3]) * (0.001f / 4.0f);
}

extern "C" void kernel_launch(void* const* d_in, const int* in_sizes, int n_in,
                              void* d_out, int out_size, void* d_ws, size_t ws_size,
                              hipStream_t stream)
{
    (void)in_sizes; (void)n_in; (void)out_size; (void)ws_size;
    const float* x = (const float*)d_in[0];
    const float* W = (const float*)d_in[1];
    float* out = (float*)d_out;
    float* ws  = (float*)d_ws;

    _Float16* whi = (_Float16*)(ws + WHI_OFF);
    _Float16* wlo = (_Float16*)(ws + WLO_OFF);
    float*    part = ws + PART_OFF;

    hipLaunchKernelGGL(wconv, dim3(64), dim3(256), 0, stream, W, whi, wlo);
    hipLaunchKernelGGL(router_main, dim3(TOKENS / 32), dim3(512), 0, stream,
                       x, whi, wlo, out, part);
    hipLaunchKernelGGL(router_aux, dim3(1), dim3(256), 0, stream, part, out);
}